// Round 5
// baseline (655.287 us; speedup 1.0000x reference)
//
#include <hip/hip_runtime.h>
#include <hip/hip_bf16.h>
#include <cstddef>

#define F_    65536
#define LP_   8
#define NL_   8192
#define DG_   64
#define D_    32
#define ITERS_ 8

typedef short bf16x8 __attribute__((ext_vector_type(8)));
typedef float f32x4 __attribute__((ext_vector_type(4)));
typedef float f32x16 __attribute__((ext_vector_type(16)));
typedef unsigned int u32x4 __attribute__((ext_vector_type(4)));

// ---------------- helpers ----------------
__device__ __forceinline__ float sigmoidf_(float x) { return 1.0f / (1.0f + __expf(-x)); }
__device__ __forceinline__ float tanhf_(float x)    { return 1.0f - 2.0f / (__expf(2.0f * x) + 1.0f); }
__device__ __forceinline__ float seluf_(float x) {
    const float a = 1.6732632423543772f, s = 1.0507009873554805f;
    return x > 0.0f ? s * x : s * a * (__expf(x) - 1.0f);
}
__device__ __forceinline__ float softplusf_(float x) { return x > 20.0f ? x : log1pf(__expf(x)); }

#define REP32(M) M(0)M(1)M(2)M(3)M(4)M(5)M(6)M(7)M(8)M(9)M(10)M(11)M(12)M(13)M(14)M(15) \
                 M(16)M(17)M(18)M(19)M(20)M(21)M(22)M(23)M(24)M(25)M(26)M(27)M(28)M(29)M(30)M(31)

// broadcast lane i's value within each 32-lane group (1 LDS-pipe instr); i must be a literal
#define BC32(src, i) __int_as_float(__builtin_amdgcn_ds_swizzle(__float_as_int(src), ((i) << 5)))

// packed f32->bf16 (RNE): r[15:0]=bf16(a), r[31:16]=bf16(b)
__device__ __forceinline__ unsigned int cvtpk_bf16(float a, float b) {
    unsigned int r;
    asm("v_cvt_pk_bf16_f32 %0, %1, %2" : "=v"(r) : "v"(a), "v"(b));
    return r;
}

// split 8 f32 into hi/lo bf16 fragments (hi + lo ~= exact f32)
__device__ __forceinline__ void mk_frag(float4 v0, float4 v1, bf16x8& hi, bf16x8& lo) {
    u32x4 uh;
    uh.x = cvtpk_bf16(v0.x, v0.y);
    uh.y = cvtpk_bf16(v0.z, v0.w);
    uh.z = cvtpk_bf16(v1.x, v1.y);
    uh.w = cvtpk_bf16(v1.z, v1.w);
    float r0 = __uint_as_float(uh.x << 16);
    float r1 = __uint_as_float(uh.x & 0xFFFF0000u);
    float r2 = __uint_as_float(uh.y << 16);
    float r3 = __uint_as_float(uh.y & 0xFFFF0000u);
    float r4 = __uint_as_float(uh.z << 16);
    float r5 = __uint_as_float(uh.z & 0xFFFF0000u);
    float r6 = __uint_as_float(uh.w << 16);
    float r7 = __uint_as_float(uh.w & 0xFFFF0000u);
    u32x4 ul;
    ul.x = cvtpk_bf16(v0.x - r0, v0.y - r1);
    ul.y = cvtpk_bf16(v0.z - r2, v0.w - r3);
    ul.z = cvtpk_bf16(v1.x - r4, v1.y - r5);
    ul.w = cvtpk_bf16(v1.z - r6, v1.w - r7);
    hi = __builtin_bit_cast(bf16x8, uh);
    lo = __builtin_bit_cast(bf16x8, ul);
}

// ---------------- init: path_state -> pss[:,8,:] ----------------
__global__ __launch_bounds__(256) void k_init_path(
    const float* __restrict__ tr, const float* __restrict__ len,
    const float* __restrict__ loss, const float* __restrict__ prop,
    const float* __restrict__ fe_w1, const float* __restrict__ fe_b1,
    const float* __restrict__ fe_w2, const float* __restrict__ fe_b2,
    float* __restrict__ pss)
{
    const int j = threadIdx.x & 31;
    const int half = (threadIdx.x >> 5) & 1;
    float w2c[32];
#pragma unroll
    for (int i = 0; i < 32; i++) w2c[i] = fe_w2[i * 32 + j];
    const float w10 = fe_w1[j], w11 = fe_w1[32 + j], w12 = fe_w1[64 + j], w13 = fe_w1[96 + j];
    const float b1 = fe_b1[j], b2 = fe_b2[j];
    const int wave = (blockIdx.x * blockDim.x + threadIdx.x) >> 6;
    const int nw = (gridDim.x * blockDim.x) >> 6;
    for (int fp = wave; fp < F_ / 2; fp += nw) {
        const int f = fp * 2 + half;
        float p0 = (tr[f]   - 0.5f) * 2.0f;
        float p1 = (len[f]  - 0.5f) * 2.0f;
        float p2 = (loss[f] - 0.1f) * 5.0f;
        float p3 = (prop[f] - 0.2f) * 3.0f;
        float h1 = seluf_(fmaf(p0, w10, fmaf(p1, w11, fmaf(p2, w12, fmaf(p3, w13, b1)))));
        float acc = b2;
#define ISTEP(i) { float hv = BC32(h1, i); acc = fmaf(hv, w2c[i], acc); }
        REP32(ISTEP)
#undef ISTEP
        pss[(size_t)f * 288 + 8 * 32 + j] = seluf_(acc);
    }
}

// ---------------- init: link load + link_state ----------------
__global__ __launch_bounds__(256) void k_init_link(
    const float* __restrict__ tr, const float* __restrict__ cap, const int* __restrict__ f2lf,
    const float* __restrict__ le_w1, const float* __restrict__ le_b1,
    const float* __restrict__ le_w2, const float* __restrict__ le_b2,
    float* __restrict__ link_state)
{
    const int lane = threadIdx.x & 63;
    const int j = lane & 31;
    float w2c[32];
#pragma unroll
    for (int i = 0; i < 32; i++) w2c[i] = le_w2[i * 32 + j];
    const float w10 = le_w1[j], w11 = le_w1[32 + j];
    const float b1 = le_b1[j], b2 = le_b2[j];
    const int wave = (blockIdx.x * blockDim.x + threadIdx.x) >> 6;
    const int nw = (gridDim.x * blockDim.x) >> 6;
    for (int l = wave; l < NL_; l += nw) {
        int fidx = f2lf[l * 64 + lane];
        float s = tr[fidx];
        s += __shfl_xor(s, 1);  s += __shfl_xor(s, 2);  s += __shfl_xor(s, 4);
        s += __shfl_xor(s, 8);  s += __shfl_xor(s, 16); s += __shfl_xor(s, 32);
        float c = cap[l];
        float load = s * (1.0f / 64.0f) / c;
        float lf0 = (c - 1.0f);
        float h1 = seluf_(fmaf(lf0, w10, fmaf(load, w11, b1)));
        float acc = b2;
#define LSTEP(i) { float hv = BC32(h1, i); acc = fmaf(hv, w2c[i], acc); }
        REP32(LSTEP)
#undef LSTEP
        if (lane < 32) link_state[l * 32 + j] = seluf_(acc);
    }
}

// ---------------- initial mx_link = link_state @ pg_w + pg_b[0] ----------------
__global__ __launch_bounds__(256) void k_mx_link(
    const float* __restrict__ link_state, const float* __restrict__ pg_w,
    const float* __restrict__ pg_b, float* __restrict__ mx_link)
{
    const int j = threadIdx.x & 31;
    const int half = (threadIdx.x >> 5) & 1;
    float wz[32], wr[32], wh[32];
#pragma unroll
    for (int i = 0; i < 32; i++) {
        wz[i] = pg_w[i * 96 + j];
        wr[i] = pg_w[i * 96 + 32 + j];
        wh[i] = pg_w[i * 96 + 64 + j];
    }
    const float b0z = pg_b[j], b0r = pg_b[32 + j], b0h = pg_b[64 + j];
    const int wave = (blockIdx.x * blockDim.x + threadIdx.x) >> 6;
    const int nw = (gridDim.x * blockDim.x) >> 6;
    for (int lp = wave; lp < NL_ / 2; lp += nw) {
        const int l = lp * 2 + half;
        float ls = link_state[l * 32 + j];
        float az = b0z, ar = b0r, ah = b0h;
#define MSTEP(i) { float lv = BC32(ls, i); az = fmaf(lv, wz[i], az); ar = fmaf(lv, wr[i], ar); ah = fmaf(lv, wh[i], ah); }
        REP32(MSTEP)
#undef MSTEP
        float* mp = mx_link + l * 96;
        mp[j] = az; mp[32 + j] = ar; mp[64 + j] = ah;
    }
}

// ---------------- per-iter: path GRU via MFMA, 16 flows per wave ----------------
// Software-pipelined: l2f prefetched 2 steps ahead, mx gather 1 step ahead.
__global__ __launch_bounds__(256, 3) void k_path(
    const float* __restrict__ mx_link, const float* __restrict__ pg_u,
    const float* __restrict__ pg_b, const int* __restrict__ l2f,
    float* __restrict__ pss)
{
    __shared__ __align__(16) float xlds[4][576];
    const int lane = threadIdx.x & 63;
    const int wid = threadIdx.x >> 6;
    const int jj = lane & 15;       // tile col / transposed-read flow
    const int g4 = lane >> 4;       // 0..3
    const int task = (blockIdx.x * blockDim.x + threadIdx.x) >> 6;   // 0..4095
    const int fb = task * 16;
    const int frow = fb + 4 * g4;

    // B fragments (U) hi/lo: tile tl covers cols [tl*16, tl*16+16)
    bf16x8 bhi[6], blo[6];
#pragma unroll
    for (int tl = 0; tl < 6; tl++) {
        const float* up = pg_u + (g4 * 8) * 96 + tl * 16 + jj;
        float4 v0 = make_float4(up[0],   up[96],  up[192], up[288]);
        float4 v1 = make_float4(up[384], up[480], up[576], up[672]);
        mk_frag(v0, v1, bhi[tl], blo[tl]);
    }
    float b1v[6];
#pragma unroll
    for (int g = 0; g < 3; g++) {
#pragma unroll
        for (int hf = 0; hf < 2; hf++)
            b1v[g * 2 + hf] = pg_b[96 + g * 32 + hf * 16 + jj];
    }
    // init A fragment from pss slot 8 (flow fb+jj, dims g4*8..+7); copy to slot 0
    float* pbase = pss + (size_t)(fb + jj) * 288;
    float4 v0 = *(const float4*)(pbase + 256 + g4 * 8);
    float4 v1 = *(const float4*)(pbase + 256 + g4 * 8 + 4);
    *(float4*)(pbase + g4 * 8)     = v0;
    *(float4*)(pbase + g4 * 8 + 4) = v1;
    bf16x8 ahi, alo;
    mk_frag(v0, v1, ahi, alo);
    // h in C layout: flows 4*g4+r, cols {jj, jj+16}
    float hC[4][2];
#pragma unroll
    for (int r = 0; r < 4; r++) {
        const float* hp = pss + (size_t)(fb + 4 * g4 + r) * 288 + 256;
        hC[r][0] = hp[jj];
        hC[r][1] = hp[jj + 16];
    }
    float* wl = &xlds[wid][0];

    // ---- prefetch: mx for t=0, links for t=1 ----
    int lk1[4];
    float mxn[3][4][2];
#pragma unroll
    for (int r = 0; r < 4; r++) {
        int lk0 = l2f[(frow + r) * 8 + 0];
        const float* mp = mx_link + lk0 * 96;
#pragma unroll
        for (int g = 0; g < 3; g++) {
            mxn[g][r][0] = mp[g * 32 + jj];
            mxn[g][r][1] = mp[g * 32 + jj + 16];
        }
    }
#pragma unroll
    for (int r = 0; r < 4; r++) lk1[r] = l2f[(frow + r) * 8 + 1];

#pragma unroll
    for (int t = 0; t < 8; t++) {
        // consume prefetched mx
        float mxv[3][4][2];
#pragma unroll
        for (int g = 0; g < 3; g++)
#pragma unroll
            for (int r = 0; r < 4; r++) {
                mxv[g][r][0] = mxn[g][r][0];
                mxv[g][r][1] = mxn[g][r][1];
            }
        // issue next-step prefetch (lands during MFMA/gates below)
        if (t < 7) {
#pragma unroll
            for (int r = 0; r < 4; r++) {
                const float* mp = mx_link + lk1[r] * 96;
#pragma unroll
                for (int g = 0; g < 3; g++) {
                    mxn[g][r][0] = mp[g * 32 + jj];
                    mxn[g][r][1] = mp[g * 32 + jj + 16];
                }
            }
            if (t < 6) {
#pragma unroll
                for (int r = 0; r < 4; r++) lk1[r] = l2f[(frow + r) * 8 + t + 2];
            }
        }
        // mh = H @ U  (hi*hi + hi*lo + lo*hi)
        f32x4 acc[6];
#pragma unroll
        for (int tl = 0; tl < 6; tl++) {
            acc[tl] = f32x4{0.0f, 0.0f, 0.0f, 0.0f};
            acc[tl] = __builtin_amdgcn_mfma_f32_16x16x32_bf16(ahi, bhi[tl], acc[tl], 0, 0, 0);
            acc[tl] = __builtin_amdgcn_mfma_f32_16x16x32_bf16(ahi, blo[tl], acc[tl], 0, 0, 0);
            acc[tl] = __builtin_amdgcn_mfma_f32_16x16x32_bf16(alo, bhi[tl], acc[tl], 0, 0, 0);
        }
        // gates + state update in C layout; stage h_new into LDS for transpose
#pragma unroll
        for (int r = 0; r < 4; r++) {
#pragma unroll
            for (int hf = 0; hf < 2; hf++) {
                float z  = sigmoidf_(mxv[0][r][hf] + acc[0 + hf][r] + b1v[0 + hf]);
                float rg = sigmoidf_(mxv[1][r][hf] + acc[2 + hf][r] + b1v[2 + hf]);
                float c  = tanhf_(mxv[2][r][hf] + rg * (acc[4 + hf][r] + b1v[4 + hf]));
                float hn = fmaf(z, hC[r][hf], (1.0f - z) * c);
                hC[r][hf] = hn;
                wl[(4 * g4 + r) * 36 + jj + hf * 16] = hn;
            }
        }
        // transposed read (lane -> flow jj, dims g4*8..+7): coalesced store + next A
        float4 n0 = *(const float4*)&wl[jj * 36 + g4 * 8];
        float4 n1 = *(const float4*)&wl[jj * 36 + g4 * 8 + 4];
        *(float4*)(pbase + (t + 1) * 32 + g4 * 8)     = n0;
        *(float4*)(pbase + (t + 1) * 32 + g4 * 8 + 4) = n1;
        if (t < 7) mk_frag(n0, n1, ahi, alo);
    }
}

// ---------------- per-iter: attention (MFMA) + aggregate + link GRU + next mx_link ----------------
// attn^T = W^T(32xj,32k) @ P^T(32k, 64p as 2 MFMAs) via mfma_f32_32x32x16_bf16.
// D layout: col=p=lane&31, rows j=(reg&3)+8*(reg>>2)+4*(lane>>5) -> softmax over j
// needs only local 16 + shfl_xor(32). All LDS traffic wave-local (no barrier).
__global__ __launch_bounds__(256, 2) void k_att_fused(
    const float* __restrict__ pss, const int* __restrict__ f2lf, const int* __restrict__ f2lp,
    const float* __restrict__ att_w, const float* __restrict__ att_b,
    const float* __restrict__ lg_w, const float* __restrict__ lg_u, const float* __restrict__ lg_b,
    const float* __restrict__ pg_w, const float* __restrict__ pg_b,
    float* __restrict__ link_state, float* __restrict__ mx_link)
{
    __shared__ float S4[4][64 * 33];
    __shared__ float xbuf[4][32];
    const int w = threadIdx.x >> 6;
    const int lane = threadIdx.x & 63;
    const int p31 = lane & 31;
    const int h = lane >> 5;
    const int l = blockIdx.x * 4 + w;
    const int j = p31;
    float* S = &S4[w][0];

    // gather own P row -> stage f32 into LDS row [lane][0..31] (stride 33, conflict-free)
    const int fi = f2lf[l * 64 + lane];
    const int pi = f2lp[l * 64 + lane];
    const float* row = pss + ((size_t)fi * 9 + pi) * 32;
#pragma unroll
    for (int i = 0; i < 8; i++) {
        float4 v = ((const float4*)row)[i];
        S[lane * 33 + 4 * i + 0] = v.x;
        S[lane * 33 + 4 * i + 1] = v.y;
        S[lane * 33 + 4 * i + 2] = v.z;
        S[lane * 33 + 4 * i + 3] = v.w;
    }

    // A fragments: W^T hi/lo, A[j=p31, k=kt*16+h*8+e] = att_w[k*32+j]
    bf16x8 awhi[2], awlo[2];
#pragma unroll
    for (int kt = 0; kt < 2; kt++) {
        const float* wp = att_w + (kt * 16 + h * 8) * 32 + p31;
        float4 a0 = make_float4(wp[0],   wp[32],  wp[64],  wp[96]);
        float4 a1 = make_float4(wp[128], wp[160], wp[192], wp[224]);
        mk_frag(a0, a1, awhi[kt], awlo[kt]);
    }
    float4 ab[4];
#pragma unroll
    for (int rg = 0; rg < 4; rg++) ab[rg] = *(const float4*)(att_b + 8 * rg + 4 * h);

    // B fragments from LDS: B[k, p] = P[p + 32ph, k]
    bf16x8 bphi[2][2], bplo[2][2];
#pragma unroll
    for (int ph = 0; ph < 2; ph++)
#pragma unroll
        for (int kt = 0; kt < 2; kt++) {
            const float* sp = S + (p31 + 32 * ph) * 33 + kt * 16 + h * 8;
            float4 b0 = make_float4(sp[0], sp[1], sp[2], sp[3]);
            float4 b1 = make_float4(sp[4], sp[5], sp[6], sp[7]);
            mk_frag(b0, b1, bphi[ph][kt], bplo[ph][kt]);
        }

    f32x16 acc0{}, acc1{};
#pragma unroll
    for (int kt = 0; kt < 2; kt++) {
        acc0 = __builtin_amdgcn_mfma_f32_32x32x16_bf16(awhi[kt], bphi[0][kt], acc0, 0, 0, 0);
        acc0 = __builtin_amdgcn_mfma_f32_32x32x16_bf16(awhi[kt], bplo[0][kt], acc0, 0, 0, 0);
        acc0 = __builtin_amdgcn_mfma_f32_32x32x16_bf16(awlo[kt], bphi[0][kt], acc0, 0, 0, 0);
        acc1 = __builtin_amdgcn_mfma_f32_32x32x16_bf16(awhi[kt], bphi[1][kt], acc1, 0, 0, 0);
        acc1 = __builtin_amdgcn_mfma_f32_32x32x16_bf16(awhi[kt], bplo[1][kt], acc1, 0, 0, 0);
        acc1 = __builtin_amdgcn_mfma_f32_32x32x16_bf16(awlo[kt], bphi[1][kt], acc1, 0, 0, 0);
    }

    // bias + leaky + softmax(over j) + q = score * P, per p-half
    float q0[16], q1[16];
#pragma unroll
    for (int ph = 0; ph < 2; ph++) {
        float v[16];
#pragma unroll
        for (int r = 0; r < 16; r++) {
            float bias = ((const float*)&ab[r >> 2])[r & 3];
            float x = (ph == 0 ? acc0[r] : acc1[r]) + bias;
            v[r] = x > 0.0f ? x : 0.2f * x;
        }
        float m = v[0];
#pragma unroll
        for (int r = 1; r < 16; r++) m = fmaxf(m, v[r]);
        m = fmaxf(m, __shfl_xor(m, 32));
        float sm = 0.0f;
#pragma unroll
        for (int r = 0; r < 16; r++) { v[r] = __expf(v[r] - m); sm += v[r]; }
        sm += __shfl_xor(sm, 32);
        float inv = 1.0f / sm;
        const float* sp = S + (p31 + 32 * ph) * 33;
        float* q = (ph == 0) ? q0 : q1;
#pragma unroll
        for (int r = 0; r < 16; r++) {
            int jr = (r & 3) + 8 * (r >> 2) + 4 * h;
            q[r] = v[r] * inv * sp[jr];
        }
    }
    // agg[j] = sum over p: butterfly over the 32-lane p dimension
    float qs[16];
#pragma unroll
    for (int r = 0; r < 16; r++) qs[r] = q0[r] + q1[r];
#pragma unroll
    for (int d = 1; d < 32; d <<= 1) {
#pragma unroll
        for (int r = 0; r < 16; r++) qs[r] += __shfl_xor(qs[r], d);
    }
    if (p31 == 0) {
#pragma unroll
        for (int r = 0; r < 16; r++) xbuf[w][(r & 3) + 8 * (r >> 2) + 4 * h] = qs[r];
    }
    float s = xbuf[w][j];   // agg[j] in all 64 lanes

    // split GRU matvecs: lanes 0-31 h-side (lg_u), lanes 32-63 x-side (lg_w)
    const float hval = link_state[l * 32 + j];
    float src = (lane < 32) ? hval : s;
    const float* wb = (lane < 32) ? lg_u : lg_w;
    float p0 = (lane < 32) ? lg_b[96 + j]      : lg_b[j];
    float p1 = (lane < 32) ? lg_b[96 + 32 + j] : lg_b[32 + j];
    float p2 = (lane < 32) ? lg_b[96 + 64 + j] : lg_b[64 + j];
#define ASTEP(i) { float vv = BC32(src, i); \
    p0 = fmaf(vv, wb[(i) * 96 + j], p0); \
    p1 = fmaf(vv, wb[(i) * 96 + 32 + j], p1); \
    p2 = fmaf(vv, wb[(i) * 96 + 64 + j], p2); }
    REP32(ASTEP)
#undef ASTEP
    float t0 = __shfl_xor(p0, 32);
    float t1 = __shfl_xor(p1, 32);
    float t2 = __shfl_xor(p2, 32);
    float hn = 0.0f;
    if (lane < 32) {
        float z = sigmoidf_(t0 + p0);
        float r = sigmoidf_(t1 + p1);
        float c = tanhf_(t2 + r * p2);
        hn = fmaf(z, hval, (1.0f - z) * c);
        link_state[l * 32 + j] = hn;
    }
    float hnb = __shfl(hn, j);   // broadcast lower-half hn to both halves
    // mx_link[l] = hn @ pg_w + pg_b[0]: lanes 0-31 do mz,mr; lanes 32-63 do mh
    float m0 = (lane < 32) ? pg_b[j]      : pg_b[64 + j];
    float m1 = (lane < 32) ? pg_b[32 + j] : 0.0f;
    const float* c0 = (lane < 32) ? pg_w + j      : pg_w + 64 + j;
    const float* c1 = (lane < 32) ? pg_w + 32 + j : pg_w + 64 + j;
#define MXS(i) { float vv = BC32(hnb, i); \
    m0 = fmaf(vv, c0[(i) * 96], m0); \
    m1 = fmaf(vv, c1[(i) * 96], m1); }
    REP32(MXS)
#undef MXS
    float* mp = mx_link + l * 96;
    if (lane < 32) { mp[j] = m0; mp[32 + j] = m1; }
    else           { mp[64 + j] = m0; }
}

// ---------------- readout ----------------
__global__ __launch_bounds__(256) void k_readout(
    const float* __restrict__ pss, const int* __restrict__ l2f,
    const float* __restrict__ cap, const float* __restrict__ prop,
    const float* __restrict__ ro_w1, const float* __restrict__ b1,
    const float* __restrict__ ro_w2, const float* __restrict__ b2,
    const float* __restrict__ w3, const float* __restrict__ b3,
    float* __restrict__ out)
{
    const int tid = blockIdx.x * blockDim.x + threadIdx.x;  // F*8 total
    const int f = tid >> 3, t = tid & 7;
    const float* row = pss + ((size_t)f * 9 + 1 + t) * 32;
    float xr[32];
#pragma unroll
    for (int i = 0; i < 8; i++) {
        float4 v = ((const float4*)row)[i];
        xr[4 * i] = v.x; xr[4 * i + 1] = v.y; xr[4 * i + 2] = v.z; xr[4 * i + 3] = v.w;
    }
    float h1[16];
#pragma unroll
    for (int jj = 0; jj < 16; jj++) {
        float acc = b1[jj];
#pragma unroll
        for (int i = 0; i < 32; i++) acc = fmaf(xr[i], ro_w1[i * 16 + jj], acc);
        h1[jj] = seluf_(acc);
    }
    float h2[8];
#pragma unroll
    for (int jj = 0; jj < 8; jj++) {
        float acc = b2[jj];
#pragma unroll
        for (int i = 0; i < 16; i++) acc = fmaf(h1[i], ro_w2[i * 8 + jj], acc);
        h2[jj] = seluf_(acc);
    }
    float o = b3[0];
#pragma unroll
    for (int i = 0; i < 8; i++) o = fmaf(h2[i], w3[i], o);
    o = softplusf_(o);
    int link = l2f[f * 8 + t];
    float v = o / cap[link];
    v += __shfl_xor(v, 1, 8);
    v += __shfl_xor(v, 2, 8);
    v += __shfl_xor(v, 4, 8);
    if (t == 0) out[f] = v + prop[f];
}

// ---------------- host ----------------
extern "C" void kernel_launch(void* const* d_in, const int* in_sizes, int n_in,
                              void* d_out, int out_size, void* d_ws, size_t ws_size,
                              hipStream_t stream) {
    const float* flow_traffic = (const float*)d_in[0];
    const float* flow_length  = (const float*)d_in[1];
    const float* flow_loss    = (const float*)d_in[2];
    const float* flow_prop    = (const float*)d_in[3];
    const float* link_cap     = (const float*)d_in[5];
    const int*   l2f          = (const int*)d_in[6];
    const int*   f2lf         = (const int*)d_in[7];
    const int*   f2lp         = (const int*)d_in[8];
    const float* fe_w1 = (const float*)d_in[9],  *fe_b1 = (const float*)d_in[10];
    const float* fe_w2 = (const float*)d_in[11], *fe_b2 = (const float*)d_in[12];
    const float* le_w1 = (const float*)d_in[13], *le_b1 = (const float*)d_in[14];
    const float* le_w2 = (const float*)d_in[15], *le_b2 = (const float*)d_in[16];
    const float* att_w = (const float*)d_in[17], *att_b = (const float*)d_in[18];
    const float* pg_w  = (const float*)d_in[19], *pg_u  = (const float*)d_in[20], *pg_b = (const float*)d_in[21];
    const float* lg_w  = (const float*)d_in[22], *lg_u  = (const float*)d_in[23], *lg_b = (const float*)d_in[24];
    const float* ro_w1 = (const float*)d_in[25], *ro_b1 = (const float*)d_in[26];
    const float* ro_w2 = (const float*)d_in[27], *ro_b2 = (const float*)d_in[28];
    const float* ro_w3 = (const float*)d_in[29], *ro_b3 = (const float*)d_in[30];
    float* out = (float*)d_out;

    float* ws = (float*)d_ws;
    float* pss        = ws;                                   // F*9*32
    float* link_state = pss + (size_t)F_ * 288;               // NL*32
    float* mx_link    = link_state + NL_ * 32;                // NL*96

    k_init_path<<<512, 256, 0, stream>>>(flow_traffic, flow_length, flow_loss, flow_prop,
                                         fe_w1, fe_b1, fe_w2, fe_b2, pss);
    k_init_link<<<512, 256, 0, stream>>>(flow_traffic, link_cap, f2lf,
                                         le_w1, le_b1, le_w2, le_b2, link_state);
    k_mx_link<<<64, 256, 0, stream>>>(link_state, pg_w, pg_b, mx_link);
    for (int it = 0; it < ITERS_; ++it) {
        k_path<<<F_ / 64, 256, 0, stream>>>(mx_link, pg_u, pg_b, l2f, pss);
        k_att_fused<<<NL_ / 4, 256, 0, stream>>>(pss, f2lf, f2lp, att_w, att_b,
                                                 lg_w, lg_u, lg_b, pg_w, pg_b,
                                                 link_state, mx_link);
    }
    k_readout<<<F_ * 8 / 256, 256, 0, stream>>>(pss, l2f, link_cap, flow_prop,
                                                ro_w1, ro_b1, ro_w2, ro_b2, ro_w3, ro_b3, out);
}